// Round 3
// baseline (149.015 us; speedup 1.0000x reference)
//
#include <hip/hip_runtime.h>
#include <hip/hip_bf16.h>

// Problem: out[b,l,:] = code[b,l,:] @ W[l]   (B=256, L=64, C=256, HW=1024, fp32)
#define B_  256
#define L_  64
#define C_  256
#define HW_ 1024

typedef float  floatx4 __attribute__((ext_vector_type(4)));
typedef __bf16 bf16x8  __attribute__((ext_vector_type(8)));
typedef __bf16 bf16x4  __attribute__((ext_vector_type(4)));

#define LDT 72   // LDS row stride in bf16 elems (144 B, 16B-aligned rows)

// Barrier that does NOT drain outstanding global loads (vmcnt): only LDS ops
// must be visible across the barrier; register prefetch stays in flight.
#define BARRIER_LDS() asm volatile("s_waitcnt lgkmcnt(0)\n\ts_barrier" ::: "memory")

// One block: 128x128 tile of group l. 512 threads = 8 waves (2x4),
// each wave 64x32 via 4x2 grid of mfma_f32_16x16x32_bf16.
// B staging uses staggered k-quads (kq = (g+i)&15) so transpose writes hit
// all 32 banks evenly (round-2 pattern was 4x bank-conflicted).
// B prefetch is depth-2 (ping-pong regs); A is depth-1.
__global__ __launch_bounds__(512, 4)
void gld_mfma_kernel(const float* __restrict__ code,
                     const float* __restrict__ W,
                     float* __restrict__ out)
{
    const int tid = threadIdx.x;
    const int l   = blockIdx.z;
    const int m0  = blockIdx.y * 128;   // batch rows
    const int n0  = blockIdx.x * 128;   // HW cols

    __shared__ __bf16 Alds[128 * LDT];  // A tile [m][k] bf16
    __shared__ __bf16 Blds[128 * LDT];  // B tile transposed [n][k] bf16

    const int lane = tid & 63;
    const int wave = tid >> 6;          // 0..7
    const int wm = (wave >> 2) * 64;    // 0,64
    const int wn = (wave & 3) * 32;     // 0,32,64,96

    floatx4 acc[4][2];
    #pragma unroll
    for (int i = 0; i < 4; ++i)
        #pragma unroll
        for (int j = 0; j < 2; ++j)
            acc[i][j] = (floatx4)0.0f;

    // A staging: 128 rows x 64 k fp32 -> 4 float4 per thread
    const int a_row = tid >> 4;          // 0..31 (4 passes of 32 rows)
    const int a_kc  = (tid & 15) * 4;    // k-chunk
    // B staging: 64 k x 128 n fp32, 4x4 micro-tile transpose with staggered k:
    const int b_i  = tid & 31;           // n-quad index (n = 4*b_i .. +3)
    const int b_g  = tid >> 5;           // 0..15
    const int b_kq = (b_g + b_i) & 15;   // staggered k-quad (k = 4*b_kq .. +3)

    const float* aBase = code + (size_t)m0 * (L_ * C_) + (size_t)l * C_ + a_kc;
    const float* wBase = W + (size_t)l * (C_ * HW_) + n0 + 4 * b_i;

    floatx4 Areg[4];      // depth-1
    floatx4 Breg[2][4];   // depth-2 ping-pong

    // ---- prologue: A(0) first (needed soonest), then B(0), B(64) ----
    #pragma unroll
    for (int p = 0; p < 4; ++p)
        Areg[p] = *(const floatx4*)(aBase + (size_t)(p * 32 + a_row) * (L_ * C_));
    #pragma unroll
    for (int r = 0; r < 4; ++r)
        Breg[0][r] = *(const floatx4*)(wBase + (size_t)(4 * b_kq + r) * HW_);
    #pragma unroll
    for (int r = 0; r < 4; ++r)
        Breg[1][r] = *(const floatx4*)(wBase + (size_t)(64 + 4 * b_kq + r) * HW_);

    #pragma unroll
    for (int kb = 0; kb < C_; kb += 64) {
        const int pb = (kb >> 6) & 1;

        // ---- B write first (its data is >=2 iters old -> no vmcnt stall) ----
        #pragma unroll
        for (int j = 0; j < 4; ++j) {
            bf16x4 h;
            h.x = (__bf16)Breg[pb][0][j]; h.y = (__bf16)Breg[pb][1][j];
            h.z = (__bf16)Breg[pb][2][j]; h.w = (__bf16)Breg[pb][3][j];
            *(bf16x4*)&Blds[(4 * b_i + j) * LDT + 4 * b_kq] = h;
        }
        // ---- A write (waits on A loads issued last iter) ----
        #pragma unroll
        for (int p = 0; p < 4; ++p) {
            bf16x4 h;
            h.x = (__bf16)Areg[p].x; h.y = (__bf16)Areg[p].y;
            h.z = (__bf16)Areg[p].z; h.w = (__bf16)Areg[p].w;
            *(bf16x4*)&Alds[(p * 32 + a_row) * LDT + a_kc] = h;
        }

        // ---- prefetches: A for kb+64 (depth-1), B for kb+128 (depth-2) ----
        if (kb + 64 < C_) {
            #pragma unroll
            for (int p = 0; p < 4; ++p)
                Areg[p] = *(const floatx4*)(aBase + (size_t)(p * 32 + a_row) * (L_ * C_) + (kb + 64));
        }
        if (kb + 128 < C_) {
            #pragma unroll
            for (int r = 0; r < 4; ++r)
                Breg[pb][r] = *(const floatx4*)(wBase + (size_t)(kb + 128 + 4 * b_kq + r) * HW_);
        }

        BARRIER_LDS();   // LDS writes visible; vmcnt NOT drained

        // ---- compute: 2 k-steps of 32 ----
        #pragma unroll
        for (int ks = 0; ks < 2; ++ks) {
            bf16x8 af[4], bfr[2];
            const int koff = ks * 32 + (lane >> 4) * 8;
            #pragma unroll
            for (int i = 0; i < 4; ++i)
                af[i] = *(const bf16x8*)&Alds[(wm + i * 16 + (lane & 15)) * LDT + koff];
            #pragma unroll
            for (int j = 0; j < 2; ++j)
                bfr[j] = *(const bf16x8*)&Blds[(wn + j * 16 + (lane & 15)) * LDT + koff];
            #pragma unroll
            for (int i = 0; i < 4; ++i)
                #pragma unroll
                for (int j = 0; j < 2; ++j)
                    acc[i][j] = __builtin_amdgcn_mfma_f32_16x16x32_bf16(af[i], bfr[j], acc[i][j], 0, 0, 0);
        }

        BARRIER_LDS();   // all waves done reading before next overwrite
    }

    // ---- epilogue: C/D layout col=lane&15, row=(lane>>4)*4+reg ----
    const int col0 = lane & 15;
    const int row0 = (lane >> 4) * 4;
    #pragma unroll
    for (int i = 0; i < 4; ++i) {
        #pragma unroll
        for (int j = 0; j < 2; ++j) {
            const int m = m0 + wm + i * 16 + row0;
            const int n = n0 + wn + j * 16 + col0;
            float* o = out + (size_t)m * (L_ * HW_) + (size_t)l * HW_ + n;
            #pragma unroll
            for (int r = 0; r < 4; ++r)
                o[(size_t)r * (L_ * HW_)] = acc[i][j][r];
        }
    }
}

extern "C" void kernel_launch(void* const* d_in, const int* in_sizes, int n_in,
                              void* d_out, int out_size, void* d_ws, size_t ws_size,
                              hipStream_t stream) {
    const float* code = (const float*)d_in[0];   // [256, 64, 256] fp32
    const float* W    = (const float*)d_in[1];   // [64, 256, 1024] fp32
    float* out        = (float*)d_out;           // [256, 64, 32, 32] fp32

    dim3 grid(HW_ / 128, B_ / 128, L_);          // (8, 2, 64)
    gld_mfma_kernel<<<grid, 512, 0, stream>>>(code, W, out);
}

// Round 4
// 145.902 us; speedup vs baseline: 1.0213x; 1.0213x over previous
//
#include <hip/hip_runtime.h>
#include <hip/hip_bf16.h>

// Problem: out[b,l,:] = code[b,l,:] @ W[l]   (B=256, L=64, C=256, HW=1024, fp32)
#define B_  256
#define L_  64
#define C_  256
#define HW_ 1024

typedef float  floatx4 __attribute__((ext_vector_type(4)));
typedef __bf16 bf16x8  __attribute__((ext_vector_type(8)));
typedef __bf16 bf16x4  __attribute__((ext_vector_type(4)));

#define LDT 72   // LDS row stride in bf16 (144 B = 16B-aligned rows; reads ~2-way)

// Barrier that does NOT drain outstanding global loads (vmcnt): only LDS ops
// must be visible across the barrier; register prefetch stays in flight.
#define BARRIER_LDS() asm volatile("s_waitcnt lgkmcnt(0)\n\ts_barrier" ::: "memory")

// B LDS rows are rotated within each quad: logical n -> physical row
//   p(n) = (n & ~3) | ((n + (n>>2)) & 3)
// Writes (lane i owns n-quad i, writes rows 4i+j) then hit uniform 4-way banks
// instead of round-2's 16-way; reads see the same address multiset (free).
__device__ __forceinline__ int rot_row(int n) {
    return (n & ~3) | ((n + (n >> 2)) & 3);
}

// One block: 128x128 tile of group l. 512 threads = 8 waves (2x4),
// each wave 64x32 via 4x2 grid of mfma_f32_16x16x32_bf16.
// Both A and B globally prefetched depth-2 (ping-pong regs); staging happens
// BEFORE this iter's prefetch issue, so every wait is vmcnt(8..12), never 0.
__global__ __launch_bounds__(512, 4)
void gld_mfma_kernel(const float* __restrict__ code,
                     const float* __restrict__ W,
                     float* __restrict__ out)
{
    const int tid = threadIdx.x;
    const int l   = blockIdx.z;
    const int m0  = blockIdx.y * 128;   // batch rows
    const int n0  = blockIdx.x * 128;   // HW cols

    __shared__ __bf16 Alds[128 * LDT];  // A tile [m][k] bf16
    __shared__ __bf16 Blds[128 * LDT];  // B tile transposed [p(n)][k] bf16

    const int lane = tid & 63;
    const int wave = tid >> 6;          // 0..7
    const int wm = (wave >> 2) * 64;    // 0,64
    const int wn = (wave & 3) * 32;     // 0,32,64,96

    floatx4 acc[4][2];
    #pragma unroll
    for (int i = 0; i < 4; ++i)
        #pragma unroll
        for (int j = 0; j < 2; ++j)
            acc[i][j] = (floatx4)0.0f;

    // A staging: 128 rows x 64 k fp32 -> 4 float4 per thread (coalesced)
    const int a_row = tid >> 4;          // 0..31 (4 passes of 32 rows)
    const int a_kc  = (tid & 15) * 4;    // k-chunk
    // B staging (round-2 coalesced pattern): thread owns 4x4 micro-tile,
    // loads 4 consecutive k-rows at its n-quad (512 B runs per instr).
    const int b_i  = tid & 31;           // n-quad (n = 4*b_i + j)
    const int b_kt = (tid >> 5) * 4;     // k-quad base 0..60

    const float* aBase = code + (size_t)m0 * (L_ * C_) + (size_t)l * C_ + a_kc;
    const float* wBase = W + (size_t)l * (C_ * HW_) + (size_t)b_kt * HW_ + n0 + 4 * b_i;

    floatx4 Areg[2][4];   // depth-2 ping-pong
    floatx4 Breg[2][4];   // depth-2 ping-pong

    // ---- prologue: A(0), A(64), B(0), B(64) ----
    #pragma unroll
    for (int p = 0; p < 4; ++p)
        Areg[0][p] = *(const floatx4*)(aBase + (size_t)(p * 32 + a_row) * (L_ * C_));
    #pragma unroll
    for (int p = 0; p < 4; ++p)
        Areg[1][p] = *(const floatx4*)(aBase + (size_t)(p * 32 + a_row) * (L_ * C_) + 64);
    #pragma unroll
    for (int r = 0; r < 4; ++r)
        Breg[0][r] = *(const floatx4*)(wBase + (size_t)r * HW_);
    #pragma unroll
    for (int r = 0; r < 4; ++r)
        Breg[1][r] = *(const floatx4*)(wBase + (size_t)(64 + r) * HW_);

    #pragma unroll
    for (int kb = 0; kb < C_; kb += 64) {
        const int pb = (kb >> 6) & 1;

        // ---- stage A: regs -> LDS (data is 2 iters old -> vmcnt(~12)) ----
        #pragma unroll
        for (int p = 0; p < 4; ++p) {
            bf16x4 h;
            h.x = (__bf16)Areg[pb][p].x; h.y = (__bf16)Areg[pb][p].y;
            h.z = (__bf16)Areg[pb][p].z; h.w = (__bf16)Areg[pb][p].w;
            *(bf16x4*)&Alds[(p * 32 + a_row) * LDT + a_kc] = h;
        }
        // ---- stage B transposed with row rotation (vmcnt(~8)) ----
        #pragma unroll
        for (int j = 0; j < 4; ++j) {
            bf16x4 h;
            h.x = (__bf16)Breg[pb][0][j]; h.y = (__bf16)Breg[pb][1][j];
            h.z = (__bf16)Breg[pb][2][j]; h.w = (__bf16)Breg[pb][3][j];
            const int prow = 4 * b_i + ((j + b_i) & 3);   // rot_row(4*b_i+j)
            *(bf16x4*)&Blds[prow * LDT + b_kt] = h;
        }

        // ---- issue depth-2 prefetch for kb+128 (after staging!) ----
        if (kb + 128 < C_) {
            #pragma unroll
            for (int p = 0; p < 4; ++p)
                Areg[pb][p] = *(const floatx4*)(aBase + (size_t)(p * 32 + a_row) * (L_ * C_) + (kb + 128));
            #pragma unroll
            for (int r = 0; r < 4; ++r)
                Breg[pb][r] = *(const floatx4*)(wBase + (size_t)(kb + 128 + r) * HW_);
        }

        BARRIER_LDS();   // LDS writes visible; vmcnt NOT drained

        // ---- compute: 2 k-steps of 32 ----
        #pragma unroll
        for (int ks = 0; ks < 2; ++ks) {
            bf16x8 af[4], bfr[2];
            const int koff = ks * 32 + (lane >> 4) * 8;
            #pragma unroll
            for (int i = 0; i < 4; ++i)
                af[i] = *(const bf16x8*)&Alds[(wm + i * 16 + (lane & 15)) * LDT + koff];
            #pragma unroll
            for (int j = 0; j < 2; ++j) {
                const int n = wn + j * 16 + (lane & 15);
                bfr[j] = *(const bf16x8*)&Blds[rot_row(n) * LDT + koff];
            }
            #pragma unroll
            for (int i = 0; i < 4; ++i)
                #pragma unroll
                for (int j = 0; j < 2; ++j)
                    acc[i][j] = __builtin_amdgcn_mfma_f32_16x16x32_bf16(af[i], bfr[j], acc[i][j], 0, 0, 0);
        }

        BARRIER_LDS();   // all waves done reading before next overwrite
    }

    // ---- epilogue: C/D layout col=lane&15, row=(lane>>4)*4+reg ----
    const int col0 = lane & 15;
    const int row0 = (lane >> 4) * 4;
    #pragma unroll
    for (int i = 0; i < 4; ++i) {
        #pragma unroll
        for (int j = 0; j < 2; ++j) {
            const int m = m0 + wm + i * 16 + row0;
            const int n = n0 + wn + j * 16 + col0;
            float* o = out + (size_t)m * (L_ * HW_) + (size_t)l * HW_ + n;
            #pragma unroll
            for (int r = 0; r < 4; ++r)
                o[(size_t)r * (L_ * HW_)] = acc[i][j][r];
        }
    }
}

extern "C" void kernel_launch(void* const* d_in, const int* in_sizes, int n_in,
                              void* d_out, int out_size, void* d_ws, size_t ws_size,
                              hipStream_t stream) {
    const float* code = (const float*)d_in[0];   // [256, 64, 256] fp32
    const float* W    = (const float*)d_in[1];   // [64, 256, 1024] fp32
    float* out        = (float*)d_out;           // [256, 64, 32, 32] fp32

    dim3 grid(HW_ / 128, B_ / 128, L_);          // (8, 2, 64)
    gld_mfma_kernel<<<grid, 512, 0, stream>>>(code, W, out);
}

// Round 5
// 132.116 us; speedup vs baseline: 1.1279x; 1.1044x over previous
//
#include <hip/hip_runtime.h>
#include <hip/hip_bf16.h>

// Problem: out[b,l,:] = code[b,l,:] @ W[l]   (B=256, L=64, C=256, HW=1024, fp32)
#define B_  256
#define L_  64
#define C_  256
#define HW_ 1024

typedef float  floatx4 __attribute__((ext_vector_type(4)));
typedef __bf16 bf16x8  __attribute__((ext_vector_type(8)));
typedef __bf16 bf16x4  __attribute__((ext_vector_type(4)));

#define LDT_A 72    // A row stride in bf16 (144 B): A write/read banks uniform (verified arithmetic)
#define LDB_ROW 128 // B row stride in BYTES (64 bf16, no pad; banks handled by XOR swizzle)

// Barrier that does NOT drain outstanding global loads (vmcnt): only LDS ops
// must be visible across the barrier; register prefetch stays in flight.
#define BARRIER_LDS() asm volatile("s_waitcnt lgkmcnt(0)\n\ts_barrier" ::: "memory")

// B LDS XOR swizzle: element (n,k) lives at byte
//   n*128 + ((c16 ^ g(n))*16) + (2k mod 16),  c16 = k/8,  g(n) = (n ^ (n>>2)) & 7
// Bank check: staging writes (rows 4i+j, wave-fixed column) -> phys bits
// {i0, i1, i0^i2} -> 16 uniform b64 starts (free). Fragment reads (chunk
// 4ks+quad, rows wn+16j+r) -> phys bits {ks^r2^j, q1^r1^r3, q0^r0^r2} ->
// 8 lanes/chunk uniform (free). Reads stay 16B-aligned (whole-chunk XOR).
__device__ __forceinline__ int bswz(int n) { return (n ^ (n >> 2)) & 7; }

// One block: 128x128 tile of group l. 512 threads = 8 waves (2x4),
// each wave 64x32 via 4x2 grid of mfma_f32_16x16x32_bf16.
// B prefetch depth-2 (ping-pong regs), A depth-1 (register budget: round-4's
// both-depth-2 spilled to scratch, +18 MB WRITE). B staged first each iter so
// the only vmcnt wait is on 1-phase-old A loads.
__global__ __launch_bounds__(512, 4)
void gld_mfma_kernel(const float* __restrict__ code,
                     const float* __restrict__ W,
                     float* __restrict__ out)
{
    const int tid = threadIdx.x;

    // XCD swizzle: id = ll + 8*(m + 2n + 16*lh), l = 8*lh + ll. All 16 blocks
    // of one filter l share id%8 (-> same XCD if dispatch round-robins), so
    // W's m-pair reuse and A's n-reuse stay in one XCD L2.
    const int id  = blockIdx.x;
    const int ll  = id & 7;
    const int inr = id >> 3;
    const int m0  = (inr & 1) * 128;        // batch rows
    const int n0  = ((inr >> 1) & 7) * 128; // HW cols
    const int l   = (inr >> 4) * 8 + ll;    // filter

    __shared__ __bf16 Alds[128 * LDT_A];              // A tile [m][k] bf16
    __shared__ unsigned char Blds[128 * LDB_ROW];     // B tile [n][k] bf16, XOR-swizzled

    const int lane = tid & 63;
    const int wave = tid >> 6;          // 0..7
    const int wm = (wave >> 2) * 64;    // 0,64
    const int wn = (wave & 3) * 32;     // 0,32,64,96

    floatx4 acc[4][2];
    #pragma unroll
    for (int i = 0; i < 4; ++i)
        #pragma unroll
        for (int j = 0; j < 2; ++j)
            acc[i][j] = (floatx4)0.0f;

    // A staging: 128 rows x 64 k fp32 -> 4 float4 per thread (coalesced)
    const int a_row = tid >> 4;          // 0..31 (4 passes of 32 rows)
    const int a_kc  = (tid & 15) * 4;    // k-chunk
    // B staging (coalesced): thread owns a 4n x 4k micro-tile; 4 float4 loads
    // of consecutive n at 4 consecutive k-rows (2x512B runs per instr).
    const int b_i  = tid & 31;           // n-quad (n = 4*b_i + j)
    const int b_c8 = tid >> 5;           // 8B k-chunk 0..15 (k = 4*b_c8 ..+3)

    const float* aBase = code + (size_t)m0 * (L_ * C_) + (size_t)l * C_ + a_kc;
    const float* wBase = W + (size_t)l * (C_ * HW_) + (size_t)(4 * b_c8) * HW_ + n0 + 4 * b_i;

    floatx4 Areg[4];      // depth-1
    floatx4 Breg[2][4];   // depth-2 ping-pong

    // ---- prologue: A(0), B(0), B(64) ----
    #pragma unroll
    for (int p = 0; p < 4; ++p)
        Areg[p] = *(const floatx4*)(aBase + (size_t)(p * 32 + a_row) * (L_ * C_));
    #pragma unroll
    for (int r = 0; r < 4; ++r)
        Breg[0][r] = *(const floatx4*)(wBase + (size_t)r * HW_);
    #pragma unroll
    for (int r = 0; r < 4; ++r)
        Breg[1][r] = *(const floatx4*)(wBase + (size_t)(64 + r) * HW_);

    // B LDS write addresses (loop-invariant): row 4*b_i+j, 8B chunk b_c8
    int bwaddr[4];
    #pragma unroll
    for (int j = 0; j < 4; ++j) {
        const int row = 4 * b_i + j;
        bwaddr[j] = row * LDB_ROW + (((b_c8 >> 1) ^ bswz(row)) << 4) + ((b_c8 & 1) << 3);
    }

    #pragma unroll
    for (int kb = 0; kb < C_; kb += 64) {
        const int pb = (kb >> 6) & 1;

        // ---- stage B first: data is 2 iters old -> no vmcnt stall ----
        #pragma unroll
        for (int j = 0; j < 4; ++j) {
            bf16x4 h;
            h.x = (__bf16)Breg[pb][0][j]; h.y = (__bf16)Breg[pb][1][j];
            h.z = (__bf16)Breg[pb][2][j]; h.w = (__bf16)Breg[pb][3][j];
            *(bf16x4*)&Blds[bwaddr[j]] = h;
        }
        // ---- stage A: waits on A loads issued last iter (vmcnt(4)) ----
        #pragma unroll
        for (int p = 0; p < 4; ++p) {
            bf16x4 h;
            h.x = (__bf16)Areg[p].x; h.y = (__bf16)Areg[p].y;
            h.z = (__bf16)Areg[p].z; h.w = (__bf16)Areg[p].w;
            *(bf16x4*)&Alds[(p * 32 + a_row) * LDT_A + a_kc] = h;
        }

        // ---- issue prefetch: A for kb+64 (depth-1), B for kb+128 (depth-2) ----
        if (kb + 64 < C_) {
            #pragma unroll
            for (int p = 0; p < 4; ++p)
                Areg[p] = *(const floatx4*)(aBase + (size_t)(p * 32 + a_row) * (L_ * C_) + (kb + 64));
        }
        if (kb + 128 < C_) {
            #pragma unroll
            for (int r = 0; r < 4; ++r)
                Breg[pb][r] = *(const floatx4*)(wBase + (size_t)(kb + 128 + r) * HW_);
        }

        BARRIER_LDS();   // LDS writes visible; vmcnt NOT drained

        // ---- compute: 2 k-steps of 32 ----
        #pragma unroll
        for (int ks = 0; ks < 2; ++ks) {
            bf16x8 af[4], bfr[2];
            const int koff = ks * 32 + (lane >> 4) * 8;
            #pragma unroll
            for (int i = 0; i < 4; ++i)
                af[i] = *(const bf16x8*)&Alds[(wm + i * 16 + (lane & 15)) * LDT_A + koff];
            #pragma unroll
            for (int j = 0; j < 2; ++j) {
                const int n = wn + j * 16 + (lane & 15);
                bfr[j] = *(const bf16x8*)&Blds[n * LDB_ROW + (((koff >> 3) ^ bswz(n)) << 4)];
            }
            #pragma unroll
            for (int i = 0; i < 4; ++i)
                #pragma unroll
                for (int j = 0; j < 2; ++j)
                    acc[i][j] = __builtin_amdgcn_mfma_f32_16x16x32_bf16(af[i], bfr[j], acc[i][j], 0, 0, 0);
        }

        BARRIER_LDS();   // all waves done reading before next overwrite
    }

    // ---- epilogue: C/D layout col=lane&15, row=(lane>>4)*4+reg ----
    const int col0 = lane & 15;
    const int row0 = (lane >> 4) * 4;
    #pragma unroll
    for (int i = 0; i < 4; ++i) {
        #pragma unroll
        for (int j = 0; j < 2; ++j) {
            const int m = m0 + wm + i * 16 + row0;
            const int n = n0 + wn + j * 16 + col0;
            float* o = out + (size_t)m * (L_ * HW_) + (size_t)l * HW_ + n;
            #pragma unroll
            for (int r = 0; r < 4; ++r)
                o[(size_t)r * (L_ * HW_)] = acc[i][j][r];
        }
    }
}

extern "C" void kernel_launch(void* const* d_in, const int* in_sizes, int n_in,
                              void* d_out, int out_size, void* d_ws, size_t ws_size,
                              hipStream_t stream) {
    const float* code = (const float*)d_in[0];   // [256, 64, 256] fp32
    const float* W    = (const float*)d_in[1];   // [64, 256, 1024] fp32
    float* out        = (float*)d_out;           // [256, 64, 32, 32] fp32

    gld_mfma_kernel<<<dim3(1024), 512, 0, stream>>>(code, W, out);
}